// Round 1
// baseline (506.598 us; speedup 1.0000x reference)
//
#include <hip/hip_runtime.h>
#include <math.h>

// Problem: 2-layer GAT. N=50000, E=800000 (+N self loops), F=128, H=8, C=32, NCLS=16.
// All fp32. Layer1: h1 = x@W1 [N,256]; per-edge softmax by dst over 8 heads; out=concat + bias + ELU.
// Layer2: hb = h2@W2 [N,16]; 1 head; out = seg_softmax-weighted sum + bias2.
// Strategy: CSR-by-dst (hist/scan/scatter, int atomics only), wave-per-dst register aggregation.
// Softmax max-subtraction skipped (shift-invariant; |e| <~ 3 so exp safe).

__device__ __forceinline__ float lrelu(float v){ return v > 0.f ? v : 0.2f*v; }

// ---------------- GEMM1: h1 = x @ W1  [N,128]@[128,256], + a_src1/a_dst1 ----------------
__global__ __launch_bounds__(256) void k_gemm1(const float* __restrict__ x,
    const float* __restrict__ W1, const float* __restrict__ as1,
    const float* __restrict__ ad1, float* __restrict__ h1,
    float* __restrict__ a_src1, float* __restrict__ a_dst1, int N)
{
  __shared__ float xs[8*128];
  int t = threadIdx.x;
  int n0 = blockIdx.x * 8;
  int remain = N - n0;
  const float4* xsrc = (const float4*)(x + (size_t)n0*128);
  float4* xl = (float4*)xs;
  if (remain >= 8) {
    xl[t] = xsrc[t];
  } else {
    int lim = remain*32;
    xl[t] = (t < lim) ? xsrc[t] : make_float4(0.f,0.f,0.f,0.f);
  }
  __syncthreads();
  float acc[8] = {0,0,0,0,0,0,0,0};
  for (int k=0; k<128; ++k) {
    float w = W1[k*256 + t];
    #pragma unroll
    for (int r=0; r<8; ++r) acc[r] += xs[r*128+k] * w;
  }
  float vs = as1[t], vd = ad1[t];
  int rows = remain < 8 ? remain : 8;
  for (int r=0; r<rows; ++r) {
    float v = acc[r];
    h1[(size_t)(n0+r)*256 + t] = v;
    float pa = v*vs, pd = v*vd;
    #pragma unroll
    for (int m=16; m>=1; m>>=1) { pa += __shfl_xor(pa, m); pd += __shfl_xor(pd, m); }
    if ((t & 31)==0) {
      int hd = t>>5;
      a_src1[(size_t)(n0+r)*8+hd] = pa;
      a_dst1[(size_t)(n0+r)*8+hd] = pd;
    }
  }
}

// ---------------- CSR build ----------------
__global__ void k_hist(const int* __restrict__ dstv, int* __restrict__ deg, int E, int Etot) {
  int e = blockIdx.x*blockDim.x + threadIdx.x;
  if (e >= Etot) return;
  int d = (e < E) ? dstv[e] : (e - E);
  atomicAdd(&deg[d], 1);
}

__global__ __launch_bounds__(256) void k_scan1(const int* __restrict__ deg,
    int* __restrict__ rowptr, int* __restrict__ bsum, int N)
{
  __shared__ int lds[256];
  int t = threadIdx.x;
  int base = blockIdx.x*1024 + t*4;
  int v0 = (base+0<N)?deg[base+0]:0;
  int v1 = (base+1<N)?deg[base+1]:0;
  int v2 = (base+2<N)?deg[base+2]:0;
  int v3 = (base+3<N)?deg[base+3]:0;
  int tot = v0+v1+v2+v3;
  lds[t]=tot; __syncthreads();
  for (int off=1; off<256; off<<=1){
    int add = (t>=off)?lds[t-off]:0;
    __syncthreads();
    lds[t] += add;
    __syncthreads();
  }
  int excl = lds[t] - tot;
  if (t==255) bsum[blockIdx.x] = lds[t];
  int run = excl;
  if (base+0<N){ rowptr[base+0]=run; run+=v0; }
  if (base+1<N){ rowptr[base+1]=run; run+=v1; }
  if (base+2<N){ rowptr[base+2]=run; run+=v2; }
  if (base+3<N){ rowptr[base+3]=run; }
}

__global__ __launch_bounds__(256) void k_scan2(int* bsum, int B){
  __shared__ int lds[256];
  int t = threadIdx.x;
  int o = (t<B)?bsum[t]:0;
  lds[t] = o; __syncthreads();
  for (int off=1; off<256; off<<=1){
    int add = (t>=off)?lds[t-off]:0;
    __syncthreads();
    lds[t]+=add;
    __syncthreads();
  }
  if (t<B) bsum[t] = lds[t]-o;
}

__global__ void k_scan3(int* __restrict__ rowptr, int* __restrict__ cursor,
                        const int* __restrict__ bsum, int N, int Etot){
  int i = blockIdx.x*blockDim.x + threadIdx.x;
  if (i < N){
    int r = rowptr[i] + bsum[i>>10];
    rowptr[i] = r;
    cursor[i] = r;
  } else if (i == N) {
    rowptr[N] = Etot;
  }
}

__global__ void k_scatter(const int* __restrict__ srcv, const int* __restrict__ dstv,
                          int* __restrict__ cursor, int* __restrict__ csr_src, int E, int Etot){
  int e = blockIdx.x*blockDim.x + threadIdx.x;
  if (e >= Etot) return;
  int s, d;
  if (e < E){ s = srcv[e]; d = dstv[e]; } else { s = e - E; d = s; }
  int pos = atomicAdd(&cursor[d], 1);
  csr_src[pos] = s;
}

// ---------------- Layer-1 aggregation: wave per dst node ----------------
// out[d,:] = (sum_e w_e * h1[src_e,:]) / (sum_e w_e + eps); + bias1; ELU -> h2
__global__ __launch_bounds__(256) void k_agg1(const float* __restrict__ h1,
    const float* __restrict__ a_src1, const float* __restrict__ a_dst1,
    const int* __restrict__ rowptr, const int* __restrict__ csr_src,
    const float* __restrict__ bias1, float* __restrict__ h2, int N)
{
  int wave = (blockIdx.x*blockDim.x + threadIdx.x) >> 6;
  if (wave >= N) return;
  int lane = threadIdx.x & 63;
  int head = lane >> 3;             // 8 lanes (32 ch as float4) per head
  float ad = a_dst1[(size_t)wave*8 + head];
  int beg = rowptr[wave], end = rowptr[wave+1];
  float4 acc = make_float4(0.f,0.f,0.f,0.f);
  float wsum = 0.f;
  for (int i=beg; i<end; ++i){
    int s = csr_src[i];
    float e = lrelu(a_src1[(size_t)s*8 + head] + ad);
    float w = __expf(e);
    wsum += w;   // identical across the head's 8 lanes
    float4 hv = *(const float4*)(h1 + (size_t)s*256 + lane*4);
    acc.x += w*hv.x; acc.y += w*hv.y; acc.z += w*hv.z; acc.w += w*hv.w;
  }
  float dinv = 1.f/(wsum + 1e-16f);
  const float4 bv = *(const float4*)(bias1 + lane*4);
  float4 o;
  o.x = acc.x*dinv + bv.x;
  o.y = acc.y*dinv + bv.y;
  o.z = acc.z*dinv + bv.z;
  o.w = acc.w*dinv + bv.w;
  o.x = o.x > 0.f ? o.x : __expf(o.x)-1.f;
  o.y = o.y > 0.f ? o.y : __expf(o.y)-1.f;
  o.z = o.z > 0.f ? o.z : __expf(o.z)-1.f;
  o.w = o.w > 0.f ? o.w : __expf(o.w)-1.f;
  *(float4*)(h2 + (size_t)wave*256 + lane*4) = o;
}

// ---------------- GEMM2: hb = h2 @ W2  [N,256]@[256,16], + a_src2/a_dst2 ----------------
__global__ __launch_bounds__(256) void k_gemm2(const float* __restrict__ h2,
    const float* __restrict__ W2, const float* __restrict__ as2, const float* __restrict__ ad2,
    float* __restrict__ hb, float* __restrict__ a_src2, float* __restrict__ a_dst2, int N)
{
  int t = threadIdx.x;
  int n = blockIdx.x*16 + (t>>4);
  int j = t & 15;
  if (n >= N) return;
  float acc = 0.f;
  const float* hr = h2 + (size_t)n*256;
  for (int k=0; k<256; ++k) acc += hr[k]*W2[k*16+j];
  hb[(size_t)n*16+j] = acc;
  float pa = acc*as2[j], pd = acc*ad2[j];
  #pragma unroll
  for (int m=8; m>=1; m>>=1){ pa += __shfl_xor(pa,m); pd += __shfl_xor(pd,m); }
  if (j==0){ a_src2[n]=pa; a_dst2[n]=pd; }
}

// ---------------- Layer-2 aggregation: wave per dst node (16 active lanes) ----------------
__global__ __launch_bounds__(256) void k_agg2(const float* __restrict__ hb,
    const float* __restrict__ a_src2, const float* __restrict__ a_dst2,
    const int* __restrict__ rowptr, const int* __restrict__ csr_src,
    const float* __restrict__ bias2, float* __restrict__ out, int N)
{
  int wave = (blockIdx.x*blockDim.x + threadIdx.x) >> 6;
  int lane = threadIdx.x & 63;
  if (wave >= N || lane >= 16) return;
  float ad = a_dst2[wave];
  int beg = rowptr[wave], end = rowptr[wave+1];
  float acc = 0.f, wsum = 0.f;
  for (int i=beg; i<end; ++i){
    int s = csr_src[i];
    float w = __expf(lrelu(a_src2[s] + ad));
    wsum += w;
    acc += w * hb[(size_t)s*16 + lane];
  }
  out[(size_t)wave*16 + lane] = acc/(wsum + 1e-16f) + bias2[lane];
}

extern "C" void kernel_launch(void* const* d_in, const int* in_sizes, int n_in,
                              void* d_out, int out_size, void* d_ws, size_t ws_size,
                              hipStream_t stream)
{
  const float* x   = (const float*)d_in[0];
  const int*   ei  = (const int*)  d_in[1];
  const float* W1  = (const float*)d_in[2];
  const float* as1 = (const float*)d_in[3];
  const float* ad1 = (const float*)d_in[4];
  const float* b1  = (const float*)d_in[5];
  const float* W2  = (const float*)d_in[6];
  const float* as2 = (const float*)d_in[7];
  const float* ad2 = (const float*)d_in[8];
  const float* b2  = (const float*)d_in[9];
  float* out = (float*)d_out;

  const int N    = in_sizes[0] / 128;       // 50000
  const int E    = in_sizes[1] / 2;         // 800000
  const int Etot = E + N;                   // self loops appended
  const int* srcv = ei;
  const int* dstv = ei + E;

  char* p = (char*)d_ws;
  auto alloc = [&](size_t bytes)->void* {
    void* r = (void*)p;
    p += (bytes + 255) & ~((size_t)255);
    return r;
  };
  float* h1      = (float*)alloc((size_t)N*256*sizeof(float));
  float* h2      = (float*)alloc((size_t)N*256*sizeof(float));
  float* a_src1  = (float*)alloc((size_t)N*8*sizeof(float));
  float* a_dst1  = (float*)alloc((size_t)N*8*sizeof(float));
  float* hb      = (float*)alloc((size_t)N*16*sizeof(float));
  float* a_src2  = (float*)alloc((size_t)N*sizeof(float));
  float* a_dst2  = (float*)alloc((size_t)N*sizeof(float));
  int*   deg     = (int*)alloc((size_t)N*sizeof(int));
  int*   rowptr  = (int*)alloc((size_t)(N+1)*sizeof(int));
  int*   cursor  = (int*)alloc((size_t)N*sizeof(int));
  int*   bsum    = (int*)alloc(256*sizeof(int));
  int*   csr_src = (int*)alloc((size_t)Etot*sizeof(int));

  // --- CSR build ---
  hipMemsetAsync(deg, 0, (size_t)N*sizeof(int), stream);
  {
    dim3 g((Etot + 255)/256), b(256);
    k_hist<<<g, b, 0, stream>>>(dstv, deg, E, Etot);
  }
  int B = (N + 1023)/1024;   // 49 blocks; k_scan2 handles B<=256
  k_scan1<<<dim3(B), dim3(256), 0, stream>>>(deg, rowptr, bsum, N);
  k_scan2<<<dim3(1), dim3(256), 0, stream>>>(bsum, B);
  k_scan3<<<dim3((N + 1 + 255)/256), dim3(256), 0, stream>>>(rowptr, cursor, bsum, N, Etot);
  {
    dim3 g((Etot + 255)/256), b(256);
    k_scatter<<<g, b, 0, stream>>>(srcv, dstv, cursor, csr_src, E, Etot);
  }

  // --- Layer 1 ---
  k_gemm1<<<dim3((N + 7)/8), dim3(256), 0, stream>>>(x, W1, as1, ad1, h1, a_src1, a_dst1, N);
  k_agg1<<<dim3((N + 3)/4), dim3(256), 0, stream>>>(h1, a_src1, a_dst1, rowptr, csr_src, b1, h2, N);

  // --- Layer 2 ---
  k_gemm2<<<dim3((N + 15)/16), dim3(256), 0, stream>>>(h2, W2, as2, ad2, hb, a_src2, a_dst2, N);
  k_agg2<<<dim3((N + 3)/4), dim3(256), 0, stream>>>(hb, a_src2, a_dst2, rowptr, csr_src, b2, out, N);
}

// Round 2
// 437.357 us; speedup vs baseline: 1.1583x; 1.1583x over previous
//
#include <hip/hip_runtime.h>
#include <hip/hip_fp16.h>
#include <math.h>

// 2-layer GAT. N=50000, E=800000 (+N self loops), F=128, H=8, C=32, NCLS=16.
// R2: h1 stored as fp16 (only consumer is the agg1 gather -> halves the 440MB
// HBM fetch that dominated R1); k_agg2 restructured to 4 edge-groups x 16 ch
// per wave (was 16/64 lanes active).

__device__ __forceinline__ float lrelu(float v){ return v > 0.f ? v : 0.2f*v; }

// ---------------- GEMM1: h1 = x @ W1  [N,128]@[128,256] (fp16 out), + a_src1/a_dst1 ----------------
__global__ __launch_bounds__(256) void k_gemm1(const float* __restrict__ x,
    const float* __restrict__ W1, const float* __restrict__ as1,
    const float* __restrict__ ad1, __half* __restrict__ h1,
    float* __restrict__ a_src1, float* __restrict__ a_dst1, int N)
{
  __shared__ float xs[8*128];
  int t = threadIdx.x;
  int n0 = blockIdx.x * 8;
  int remain = N - n0;
  const float4* xsrc = (const float4*)(x + (size_t)n0*128);
  float4* xl = (float4*)xs;
  if (remain >= 8) {
    xl[t] = xsrc[t];
  } else {
    int lim = remain*32;
    xl[t] = (t < lim) ? xsrc[t] : make_float4(0.f,0.f,0.f,0.f);
  }
  __syncthreads();
  float acc[8] = {0,0,0,0,0,0,0,0};
  for (int k=0; k<128; ++k) {
    float w = W1[k*256 + t];
    #pragma unroll
    for (int r=0; r<8; ++r) acc[r] += xs[r*128+k] * w;
  }
  float vs = as1[t], vd = ad1[t];
  int rows = remain < 8 ? remain : 8;
  for (int r=0; r<rows; ++r) {
    float v = acc[r];
    h1[(size_t)(n0+r)*256 + t] = __float2half(v);
    float pa = v*vs, pd = v*vd;
    #pragma unroll
    for (int m=16; m>=1; m>>=1) { pa += __shfl_xor(pa, m); pd += __shfl_xor(pd, m); }
    if ((t & 31)==0) {
      int hd = t>>5;
      a_src1[(size_t)(n0+r)*8+hd] = pa;
      a_dst1[(size_t)(n0+r)*8+hd] = pd;
    }
  }
}

// ---------------- CSR build ----------------
__global__ void k_hist(const int* __restrict__ dstv, int* __restrict__ deg, int E, int Etot) {
  int e = blockIdx.x*blockDim.x + threadIdx.x;
  if (e >= Etot) return;
  int d = (e < E) ? dstv[e] : (e - E);
  atomicAdd(&deg[d], 1);
}

__global__ __launch_bounds__(256) void k_scan1(const int* __restrict__ deg,
    int* __restrict__ rowptr, int* __restrict__ bsum, int N)
{
  __shared__ int lds[256];
  int t = threadIdx.x;
  int base = blockIdx.x*1024 + t*4;
  int v0 = (base+0<N)?deg[base+0]:0;
  int v1 = (base+1<N)?deg[base+1]:0;
  int v2 = (base+2<N)?deg[base+2]:0;
  int v3 = (base+3<N)?deg[base+3]:0;
  int tot = v0+v1+v2+v3;
  lds[t]=tot; __syncthreads();
  for (int off=1; off<256; off<<=1){
    int add = (t>=off)?lds[t-off]:0;
    __syncthreads();
    lds[t] += add;
    __syncthreads();
  }
  int excl = lds[t] - tot;
  if (t==255) bsum[blockIdx.x] = lds[t];
  int run = excl;
  if (base+0<N){ rowptr[base+0]=run; run+=v0; }
  if (base+1<N){ rowptr[base+1]=run; run+=v1; }
  if (base+2<N){ rowptr[base+2]=run; run+=v2; }
  if (base+3<N){ rowptr[base+3]=run; }
}

__global__ __launch_bounds__(256) void k_scan2(int* bsum, int B){
  __shared__ int lds[256];
  int t = threadIdx.x;
  int o = (t<B)?bsum[t]:0;
  lds[t] = o; __syncthreads();
  for (int off=1; off<256; off<<=1){
    int add = (t>=off)?lds[t-off]:0;
    __syncthreads();
    lds[t]+=add;
    __syncthreads();
  }
  if (t<B) bsum[t] = lds[t]-o;
}

__global__ void k_scan3(int* __restrict__ rowptr, int* __restrict__ cursor,
                        const int* __restrict__ bsum, int N, int Etot){
  int i = blockIdx.x*blockDim.x + threadIdx.x;
  if (i < N){
    int r = rowptr[i] + bsum[i>>10];
    rowptr[i] = r;
    cursor[i] = r;
  } else if (i == N) {
    rowptr[N] = Etot;
  }
}

__global__ void k_scatter(const int* __restrict__ srcv, const int* __restrict__ dstv,
                          int* __restrict__ cursor, int* __restrict__ csr_src, int E, int Etot){
  int e = blockIdx.x*blockDim.x + threadIdx.x;
  if (e >= Etot) return;
  int s, d;
  if (e < E){ s = srcv[e]; d = dstv[e]; } else { s = e - E; d = s; }
  int pos = atomicAdd(&cursor[d], 1);
  csr_src[pos] = s;
}

// ---------------- Layer-1 aggregation: wave per dst node (fp16 gather) ----------------
__global__ __launch_bounds__(256) void k_agg1(const __half* __restrict__ h1,
    const float* __restrict__ a_src1, const float* __restrict__ a_dst1,
    const int* __restrict__ rowptr, const int* __restrict__ csr_src,
    const float* __restrict__ bias1, float* __restrict__ h2, int N)
{
  int wave = (blockIdx.x*blockDim.x + threadIdx.x) >> 6;
  if (wave >= N) return;
  int lane = threadIdx.x & 63;
  int head = lane >> 3;             // 8 lanes (32 ch, 4 fp16 each) per head
  float ad = a_dst1[(size_t)wave*8 + head];
  int beg = rowptr[wave], end = rowptr[wave+1];
  float4 acc = make_float4(0.f,0.f,0.f,0.f);
  float wsum = 0.f;
  for (int i=beg; i<end; ++i){
    int s = csr_src[i];
    float e = lrelu(a_src1[(size_t)s*8 + head] + ad);
    float w = __expf(e);
    wsum += w;   // identical across the head's 8 lanes
    const __half2* hp = (const __half2*)(h1 + (size_t)s*256 + lane*4);
    float2 f0 = __half22float2(hp[0]);
    float2 f1 = __half22float2(hp[1]);
    acc.x += w*f0.x; acc.y += w*f0.y; acc.z += w*f1.x; acc.w += w*f1.y;
  }
  float dinv = 1.f/(wsum + 1e-16f);
  const float4 bv = *(const float4*)(bias1 + lane*4);
  float4 o;
  o.x = acc.x*dinv + bv.x;
  o.y = acc.y*dinv + bv.y;
  o.z = acc.z*dinv + bv.z;
  o.w = acc.w*dinv + bv.w;
  o.x = o.x > 0.f ? o.x : __expf(o.x)-1.f;
  o.y = o.y > 0.f ? o.y : __expf(o.y)-1.f;
  o.z = o.z > 0.f ? o.z : __expf(o.z)-1.f;
  o.w = o.w > 0.f ? o.w : __expf(o.w)-1.f;
  *(float4*)(h2 + (size_t)wave*256 + lane*4) = o;
}

// ---------------- GEMM2: hb = h2 @ W2  [N,256]@[256,16], + a_src2/a_dst2 ----------------
__global__ __launch_bounds__(256) void k_gemm2(const float* __restrict__ h2,
    const float* __restrict__ W2, const float* __restrict__ as2, const float* __restrict__ ad2,
    float* __restrict__ hb, float* __restrict__ a_src2, float* __restrict__ a_dst2, int N)
{
  int t = threadIdx.x;
  int n = blockIdx.x*16 + (t>>4);
  int j = t & 15;
  if (n >= N) return;
  float acc = 0.f;
  const float* hr = h2 + (size_t)n*256;
  for (int k=0; k<256; ++k) acc += hr[k]*W2[k*16+j];
  hb[(size_t)n*16+j] = acc;
  float pa = acc*as2[j], pd = acc*ad2[j];
  #pragma unroll
  for (int m=8; m>=1; m>>=1){ pa += __shfl_xor(pa,m); pd += __shfl_xor(pd,m); }
  if (j==0){ a_src2[n]=pa; a_dst2[n]=pd; }
}

// ---------------- Layer-2 aggregation: wave per dst, 4 edge-groups x 16 ch ----------------
__global__ __launch_bounds__(256) void k_agg2(const float* __restrict__ hb,
    const float* __restrict__ a_src2, const float* __restrict__ a_dst2,
    const int* __restrict__ rowptr, const int* __restrict__ csr_src,
    const float* __restrict__ bias2, float* __restrict__ out, int N)
{
  int wave = (blockIdx.x*blockDim.x + threadIdx.x) >> 6;
  if (wave >= N) return;
  int lane = threadIdx.x & 63;
  int eg   = lane >> 4;      // edge group 0..3
  int ch   = lane & 15;      // output channel
  float ad = a_dst2[wave];
  int beg = rowptr[wave], end = rowptr[wave+1];
  float acc = 0.f, wsum = 0.f;
  for (int i=beg+eg; i<end; i+=4){
    int s = csr_src[i];
    float w = __expf(lrelu(a_src2[s] + ad));
    wsum += w;
    acc += w * hb[(size_t)s*16 + ch];
  }
  // reduce across the 4 edge groups (lanes l, l^16, l^32, l^48)
  acc  += __shfl_xor(acc, 16);  acc  += __shfl_xor(acc, 32);
  wsum += __shfl_xor(wsum, 16); wsum += __shfl_xor(wsum, 32);
  if (eg == 0)
    out[(size_t)wave*16 + ch] = acc/(wsum + 1e-16f) + bias2[ch];
}

extern "C" void kernel_launch(void* const* d_in, const int* in_sizes, int n_in,
                              void* d_out, int out_size, void* d_ws, size_t ws_size,
                              hipStream_t stream)
{
  const float* x   = (const float*)d_in[0];
  const int*   ei  = (const int*)  d_in[1];
  const float* W1  = (const float*)d_in[2];
  const float* as1 = (const float*)d_in[3];
  const float* ad1 = (const float*)d_in[4];
  const float* b1  = (const float*)d_in[5];
  const float* W2  = (const float*)d_in[6];
  const float* as2 = (const float*)d_in[7];
  const float* ad2 = (const float*)d_in[8];
  const float* b2  = (const float*)d_in[9];
  float* out = (float*)d_out;

  const int N    = in_sizes[0] / 128;       // 50000
  const int E    = in_sizes[1] / 2;         // 800000
  const int Etot = E + N;                   // self loops appended
  const int* srcv = ei;
  const int* dstv = ei + E;

  char* p = (char*)d_ws;
  auto alloc = [&](size_t bytes)->void* {
    void* r = (void*)p;
    p += (bytes + 255) & ~((size_t)255);
    return r;
  };
  __half* h1     = (__half*)alloc((size_t)N*256*sizeof(__half));
  float* h2      = (float*)alloc((size_t)N*256*sizeof(float));
  float* a_src1  = (float*)alloc((size_t)N*8*sizeof(float));
  float* a_dst1  = (float*)alloc((size_t)N*8*sizeof(float));
  float* hb      = (float*)alloc((size_t)N*16*sizeof(float));
  float* a_src2  = (float*)alloc((size_t)N*sizeof(float));
  float* a_dst2  = (float*)alloc((size_t)N*sizeof(float));
  int*   deg     = (int*)alloc((size_t)N*sizeof(int));
  int*   rowptr  = (int*)alloc((size_t)(N+1)*sizeof(int));
  int*   cursor  = (int*)alloc((size_t)N*sizeof(int));
  int*   bsum    = (int*)alloc(256*sizeof(int));
  int*   csr_src = (int*)alloc((size_t)Etot*sizeof(int));

  // --- CSR build ---
  hipMemsetAsync(deg, 0, (size_t)N*sizeof(int), stream);
  {
    dim3 g((Etot + 255)/256), b(256);
    k_hist<<<g, b, 0, stream>>>(dstv, deg, E, Etot);
  }
  int B = (N + 1023)/1024;   // 49 blocks; k_scan2 handles B<=256
  k_scan1<<<dim3(B), dim3(256), 0, stream>>>(deg, rowptr, bsum, N);
  k_scan2<<<dim3(1), dim3(256), 0, stream>>>(bsum, B);
  k_scan3<<<dim3((N + 1 + 255)/256), dim3(256), 0, stream>>>(rowptr, cursor, bsum, N, Etot);
  {
    dim3 g((Etot + 255)/256), b(256);
    k_scatter<<<g, b, 0, stream>>>(srcv, dstv, cursor, csr_src, E, Etot);
  }

  // --- Layer 1 ---
  k_gemm1<<<dim3((N + 7)/8), dim3(256), 0, stream>>>(x, W1, as1, ad1, h1, a_src1, a_dst1, N);
  k_agg1<<<dim3((N + 3)/4), dim3(256), 0, stream>>>(h1, a_src1, a_dst1, rowptr, csr_src, b1, h2, N);

  // --- Layer 2 ---
  k_gemm2<<<dim3((N + 15)/16), dim3(256), 0, stream>>>(h2, W2, as2, ad2, hb, a_src2, a_dst2, N);
  k_agg2<<<dim3((N + 3)/4), dim3(256), 0, stream>>>(hb, a_src2, a_dst2, rowptr, csr_src, b2, out, N);
}

// Round 3
// 376.559 us; speedup vs baseline: 1.3453x; 1.1615x over previous
//
#include <hip/hip_runtime.h>
#include <hip/hip_fp16.h>
#include <math.h>

// 2-layer GAT. N=50000, E=800000 (+N self loops), F=128, H=8, C=32, NCLS=16.
// R3: (a) k_gemm1 rewritten as fp16 MFMA (16x16x32_f16), x converted during LDS
//     staging, W1 pre-transposed to fp16 [256][128]; epilogue repacks acc to LDS,
//     vector-stores fp16 h1, computes a_src1/a_dst1 from the LDS tile.
//     (b) k_agg1 edge loop unrolled x4 (4 independent load chains -> MLP).

typedef _Float16 f16x8 __attribute__((ext_vector_type(8)));
typedef float    f32x4 __attribute__((ext_vector_type(4)));

__device__ __forceinline__ float lrelu(float v){ return v > 0.f ? v : 0.2f*v; }

// ---------------- W1 transpose+convert: [128][256] fp32 -> [256][128] fp16 ----------------
__global__ void k_w1t(const float* __restrict__ W1, _Float16* __restrict__ W1t){
  int k = blockIdx.x;      // 0..127
  int n = threadIdx.x;     // 0..255
  W1t[n*128 + k] = (_Float16)W1[k*256 + n];
}

// ---------------- GEMM1 (MFMA): h1 = x @ W1 -> fp16 [N,256], + a_src1/a_dst1 ----------------
// Block: 256 thr = 4 waves; tile M=64 (wave: 16 rows x 256 cols), K=128 (4 MFMA k-steps).
__global__ __launch_bounds__(256) void k_gemm1(const float* __restrict__ x,
    const _Float16* __restrict__ W1t, const float* __restrict__ as1,
    const float* __restrict__ ad1, _Float16* __restrict__ h1,
    float* __restrict__ a_src1, float* __restrict__ a_dst1, int N)
{
  __shared__ char smem[33792];              // A-tile (17408 B) then reused for h-repack (33792 B)
  _Float16* As = (_Float16*)smem;           // [64 rows][136 halves] (272 B stride, 16B-aligned)
  int t = threadIdx.x;
  int n0 = blockIdx.x*64;

  // stage A: read x fp32 (coalesced float4), convert, write fp16 to LDS
  #pragma unroll
  for (int it=0; it<8; ++it){
    int c = it*256 + t;                     // 0..2047 chunk of float4
    int row = c >> 5;                       // 0..63
    int c4  = c & 31;                       // float4 within row
    int gr = n0 + row; if (gr > N-1) gr = N-1;
    float4 v = *(const float4*)(x + (size_t)gr*128 + c4*4);
    _Float16* dp = As + row*136 + c4*4;
    dp[0]=(_Float16)v.x; dp[1]=(_Float16)v.y; dp[2]=(_Float16)v.z; dp[3]=(_Float16)v.w;
  }
  __syncthreads();

  int wv = t>>6, lane = t&63;
  int m = lane&15, q = lane>>4;
  int r0w = wv*16;                          // wave's row offset in block

  // A fragments: lane holds A[m][ks*32 + q*8 + j], j=0..7  (16B contiguous in LDS)
  f16x8 afr[4];
  #pragma unroll
  for (int ks=0; ks<4; ++ks)
    afr[ks] = *(const f16x8*)((const char*)As + (r0w+m)*272 + ks*64 + q*16);

  f32x4 acc[16];
  #pragma unroll
  for (int ct=0; ct<16; ++ct) acc[ct] = (f32x4){0.f,0.f,0.f,0.f};

  // B fragments straight from global (W1t is 64KB, L2-resident)
  const char* bbase = (const char*)W1t;
  #pragma unroll
  for (int ct=0; ct<16; ++ct){
    const char* bp = bbase + (ct*16 + m)*256 + q*16;
    f16x8 b0 = *(const f16x8*)(bp);
    f16x8 b1 = *(const f16x8*)(bp+64);
    f16x8 b2 = *(const f16x8*)(bp+128);
    f16x8 b3 = *(const f16x8*)(bp+192);
    acc[ct] = __builtin_amdgcn_mfma_f32_16x16x32_f16(afr[0], b0, acc[ct],0,0,0);
    acc[ct] = __builtin_amdgcn_mfma_f32_16x16x32_f16(afr[1], b1, acc[ct],0,0,0);
    acc[ct] = __builtin_amdgcn_mfma_f32_16x16x32_f16(afr[2], b2, acc[ct],0,0,0);
    acc[ct] = __builtin_amdgcn_mfma_f32_16x16x32_f16(afr[3], b3, acc[ct],0,0,0);
  }
  __syncthreads();                          // all waves done reading As

  // repack: C/D layout col=lane&15, row=q*4+reg -> LDS fp16 [64 rows][264 halves] (528B stride)
  _Float16* Hs = (_Float16*)smem;
  #pragma unroll
  for (int ct=0; ct<16; ++ct){
    #pragma unroll
    for (int r=0; r<4; ++r)
      Hs[(size_t)(r0w + q*4 + r)*264 + ct*16 + m] = (_Float16)acc[ct][r];
  }
  __syncthreads();

  // h1 store: wave stores its own 16 rows (8B per lane per row)
  for (int r=0; r<16; ++r){
    int grow = n0 + r0w + r;
    if (grow < N){
      uint2 v = *(const uint2*)((const char*)Hs + (size_t)(r0w+r)*528 + lane*8);
      *(uint2*)((char*)h1 + (size_t)grow*512 + lane*8) = v;
    }
  }

  // a_src1/a_dst1: 512 (row,head) pairs per block, 2 per thread
  #pragma unroll
  for (int p=t; p<512; p+=256){
    int row = p>>3, hd = p&7;
    int grow = n0 + row;
    if (grow < N){
      const _Float16* hr = Hs + (size_t)row*264 + hd*32;
      float sa=0.f, sd=0.f;
      #pragma unroll
      for (int c=0; c<32; ++c){
        float hv = (float)hr[c];
        sa += hv * as1[hd*32+c];
        sd += hv * ad1[hd*32+c];
      }
      a_src1[(size_t)grow*8+hd] = sa;
      a_dst1[(size_t)grow*8+hd] = sd;
    }
  }
}

// ---------------- CSR build ----------------
__global__ void k_hist(const int* __restrict__ dstv, int* __restrict__ deg, int E, int Etot) {
  int e = blockIdx.x*blockDim.x + threadIdx.x;
  if (e >= Etot) return;
  int d = (e < E) ? dstv[e] : (e - E);
  atomicAdd(&deg[d], 1);
}

__global__ __launch_bounds__(256) void k_scan1(const int* __restrict__ deg,
    int* __restrict__ rowptr, int* __restrict__ bsum, int N)
{
  __shared__ int lds[256];
  int t = threadIdx.x;
  int base = blockIdx.x*1024 + t*4;
  int v0 = (base+0<N)?deg[base+0]:0;
  int v1 = (base+1<N)?deg[base+1]:0;
  int v2 = (base+2<N)?deg[base+2]:0;
  int v3 = (base+3<N)?deg[base+3]:0;
  int tot = v0+v1+v2+v3;
  lds[t]=tot; __syncthreads();
  for (int off=1; off<256; off<<=1){
    int add = (t>=off)?lds[t-off]:0;
    __syncthreads();
    lds[t] += add;
    __syncthreads();
  }
  int excl = lds[t] - tot;
  if (t==255) bsum[blockIdx.x] = lds[t];
  int run = excl;
  if (base+0<N){ rowptr[base+0]=run; run+=v0; }
  if (base+1<N){ rowptr[base+1]=run; run+=v1; }
  if (base+2<N){ rowptr[base+2]=run; run+=v2; }
  if (base+3<N){ rowptr[base+3]=run; }
}

__global__ __launch_bounds__(256) void k_scan2(int* bsum, int B){
  __shared__ int lds[256];
  int t = threadIdx.x;
  int o = (t<B)?bsum[t]:0;
  lds[t] = o; __syncthreads();
  for (int off=1; off<256; off<<=1){
    int add = (t>=off)?lds[t-off]:0;
    __syncthreads();
    lds[t]+=add;
    __syncthreads();
  }
  if (t<B) bsum[t] = lds[t]-o;
}

__global__ void k_scan3(int* __restrict__ rowptr, int* __restrict__ cursor,
                        const int* __restrict__ bsum, int N, int Etot){
  int i = blockIdx.x*blockDim.x + threadIdx.x;
  if (i < N){
    int r = rowptr[i] + bsum[i>>10];
    rowptr[i] = r;
    cursor[i] = r;
  } else if (i == N) {
    rowptr[N] = Etot;
  }
}

__global__ void k_scatter(const int* __restrict__ srcv, const int* __restrict__ dstv,
                          int* __restrict__ cursor, int* __restrict__ csr_src, int E, int Etot){
  int e = blockIdx.x*blockDim.x + threadIdx.x;
  if (e >= Etot) return;
  int s, d;
  if (e < E){ s = srcv[e]; d = dstv[e]; } else { s = e - E; d = s; }
  int pos = atomicAdd(&cursor[d], 1);
  csr_src[pos] = s;
}

// ---------------- Layer-1 aggregation: wave per dst node, x4 unrolled ----------------
__global__ __launch_bounds__(256) void k_agg1(const __half* __restrict__ h1,
    const float* __restrict__ a_src1, const float* __restrict__ a_dst1,
    const int* __restrict__ rowptr, const int* __restrict__ csr_src,
    const float* __restrict__ bias1, float* __restrict__ h2, int N)
{
  int wave = (blockIdx.x*blockDim.x + threadIdx.x) >> 6;
  if (wave >= N) return;
  int lane = threadIdx.x & 63;
  int head = lane >> 3;             // 8 lanes (32 ch, 4 fp16 each) per head
  float ad = a_dst1[(size_t)wave*8 + head];
  int beg = rowptr[wave], end = rowptr[wave+1];
  float4 acc = make_float4(0.f,0.f,0.f,0.f);
  float wsum = 0.f;
  int i = beg;
  for (; i+4 <= end; i+=4){
    int s0=csr_src[i], s1=csr_src[i+1], s2=csr_src[i+2], s3=csr_src[i+3];
    float e0=a_src1[(size_t)s0*8+head], e1=a_src1[(size_t)s1*8+head];
    float e2=a_src1[(size_t)s2*8+head], e3=a_src1[(size_t)s3*8+head];
    uint2 p0 = *(const uint2*)((const char*)h1 + (size_t)s0*512 + lane*8);
    uint2 p1 = *(const uint2*)((const char*)h1 + (size_t)s1*512 + lane*8);
    uint2 p2 = *(const uint2*)((const char*)h1 + (size_t)s2*512 + lane*8);
    uint2 p3 = *(const uint2*)((const char*)h1 + (size_t)s3*512 + lane*8);
    float w0=__expf(lrelu(e0+ad)), w1=__expf(lrelu(e1+ad));
    float w2=__expf(lrelu(e2+ad)), w3=__expf(lrelu(e3+ad));
    wsum += (w0+w1)+(w2+w3);
    const __half2* q0=(const __half2*)&p0; const __half2* q1=(const __half2*)&p1;
    const __half2* q2=(const __half2*)&p2; const __half2* q3=(const __half2*)&p3;
    float2 a0=__half22float2(q0[0]), b0=__half22float2(q0[1]);
    float2 a1=__half22float2(q1[0]), b1=__half22float2(q1[1]);
    float2 a2=__half22float2(q2[0]), b2=__half22float2(q2[1]);
    float2 a3=__half22float2(q3[0]), b3=__half22float2(q3[1]);
    acc.x += w0*a0.x + w1*a1.x + w2*a2.x + w3*a3.x;
    acc.y += w0*a0.y + w1*a1.y + w2*a2.y + w3*a3.y;
    acc.z += w0*b0.x + w1*b1.x + w2*b2.x + w3*b3.x;
    acc.w += w0*b0.y + w1*b1.y + w2*b2.y + w3*b3.y;
  }
  for (; i<end; ++i){
    int s = csr_src[i];
    float w = __expf(lrelu(a_src1[(size_t)s*8+head] + ad));
    wsum += w;
    uint2 p = *(const uint2*)((const char*)h1 + (size_t)s*512 + lane*8);
    const __half2* qq=(const __half2*)&p;
    float2 f0=__half22float2(qq[0]), f1=__half22float2(qq[1]);
    acc.x += w*f0.x; acc.y += w*f0.y; acc.z += w*f1.x; acc.w += w*f1.y;
  }
  float dinv = 1.f/(wsum + 1e-16f);
  const float4 bv = *(const float4*)(bias1 + lane*4);
  float4 o;
  o.x = acc.x*dinv + bv.x;
  o.y = acc.y*dinv + bv.y;
  o.z = acc.z*dinv + bv.z;
  o.w = acc.w*dinv + bv.w;
  o.x = o.x > 0.f ? o.x : __expf(o.x)-1.f;
  o.y = o.y > 0.f ? o.y : __expf(o.y)-1.f;
  o.z = o.z > 0.f ? o.z : __expf(o.z)-1.f;
  o.w = o.w > 0.f ? o.w : __expf(o.w)-1.f;
  *(float4*)(h2 + (size_t)wave*256 + lane*4) = o;
}

// ---------------- GEMM2: hb = h2 @ W2  [N,256]@[256,16], + a_src2/a_dst2 ----------------
__global__ __launch_bounds__(256) void k_gemm2(const float* __restrict__ h2,
    const float* __restrict__ W2, const float* __restrict__ as2, const float* __restrict__ ad2,
    float* __restrict__ hb, float* __restrict__ a_src2, float* __restrict__ a_dst2, int N)
{
  int t = threadIdx.x;
  int n = blockIdx.x*16 + (t>>4);
  int j = t & 15;
  if (n >= N) return;
  float acc = 0.f;
  const float* hr = h2 + (size_t)n*256;
  for (int k=0; k<256; ++k) acc += hr[k]*W2[k*16+j];
  hb[(size_t)n*16+j] = acc;
  float pa = acc*as2[j], pd = acc*ad2[j];
  #pragma unroll
  for (int m=8; m>=1; m>>=1){ pa += __shfl_xor(pa,m); pd += __shfl_xor(pd,m); }
  if (j==0){ a_src2[n]=pa; a_dst2[n]=pd; }
}

// ---------------- Layer-2 aggregation: wave per dst, 4 edge-groups x 16 ch ----------------
__global__ __launch_bounds__(256) void k_agg2(const float* __restrict__ hb,
    const float* __restrict__ a_src2, const float* __restrict__ a_dst2,
    const int* __restrict__ rowptr, const int* __restrict__ csr_src,
    const float* __restrict__ bias2, float* __restrict__ out, int N)
{
  int wave = (blockIdx.x*blockDim.x + threadIdx.x) >> 6;
  if (wave >= N) return;
  int lane = threadIdx.x & 63;
  int eg   = lane >> 4;      // edge group 0..3
  int ch   = lane & 15;      // output channel
  float ad = a_dst2[wave];
  int beg = rowptr[wave], end = rowptr[wave+1];
  float acc = 0.f, wsum = 0.f;
  for (int i=beg+eg; i<end; i+=4){
    int s = csr_src[i];
    float w = __expf(lrelu(a_src2[s] + ad));
    wsum += w;
    acc += w * hb[(size_t)s*16 + ch];
  }
  acc  += __shfl_xor(acc, 16);  acc  += __shfl_xor(acc, 32);
  wsum += __shfl_xor(wsum, 16); wsum += __shfl_xor(wsum, 32);
  if (eg == 0)
    out[(size_t)wave*16 + ch] = acc/(wsum + 1e-16f) + bias2[ch];
}

extern "C" void kernel_launch(void* const* d_in, const int* in_sizes, int n_in,
                              void* d_out, int out_size, void* d_ws, size_t ws_size,
                              hipStream_t stream)
{
  const float* x   = (const float*)d_in[0];
  const int*   ei  = (const int*)  d_in[1];
  const float* W1  = (const float*)d_in[2];
  const float* as1 = (const float*)d_in[3];
  const float* ad1 = (const float*)d_in[4];
  const float* b1  = (const float*)d_in[5];
  const float* W2  = (const float*)d_in[6];
  const float* as2 = (const float*)d_in[7];
  const float* ad2 = (const float*)d_in[8];
  const float* b2  = (const float*)d_in[9];
  float* out = (float*)d_out;

  const int N    = in_sizes[0] / 128;       // 50000
  const int E    = in_sizes[1] / 2;         // 800000
  const int Etot = E + N;                   // self loops appended
  const int* srcv = ei;
  const int* dstv = ei + E;

  char* p = (char*)d_ws;
  auto alloc = [&](size_t bytes)->void* {
    void* r = (void*)p;
    p += (bytes + 255) & ~((size_t)255);
    return r;
  };
  _Float16* h1   = (_Float16*)alloc((size_t)N*256*sizeof(_Float16));
  _Float16* W1t  = (_Float16*)alloc((size_t)256*128*sizeof(_Float16));
  float* h2      = (float*)alloc((size_t)N*256*sizeof(float));
  float* a_src1  = (float*)alloc((size_t)N*8*sizeof(float));
  float* a_dst1  = (float*)alloc((size_t)N*8*sizeof(float));
  float* hb      = (float*)alloc((size_t)N*16*sizeof(float));
  float* a_src2  = (float*)alloc((size_t)N*sizeof(float));
  float* a_dst2  = (float*)alloc((size_t)N*sizeof(float));
  int*   deg     = (int*)alloc((size_t)N*sizeof(int));
  int*   rowptr  = (int*)alloc((size_t)(N+1)*sizeof(int));
  int*   cursor  = (int*)alloc((size_t)N*sizeof(int));
  int*   bsum    = (int*)alloc(256*sizeof(int));
  int*   csr_src = (int*)alloc((size_t)Etot*sizeof(int));

  // --- CSR build ---
  hipMemsetAsync(deg, 0, (size_t)N*sizeof(int), stream);
  {
    dim3 g((Etot + 255)/256), b(256);
    k_hist<<<g, b, 0, stream>>>(dstv, deg, E, Etot);
  }
  int B = (N + 1023)/1024;
  k_scan1<<<dim3(B), dim3(256), 0, stream>>>(deg, rowptr, bsum, N);
  k_scan2<<<dim3(1), dim3(256), 0, stream>>>(bsum, B);
  k_scan3<<<dim3((N + 1 + 255)/256), dim3(256), 0, stream>>>(rowptr, cursor, bsum, N, Etot);
  {
    dim3 g((Etot + 255)/256), b(256);
    k_scatter<<<g, b, 0, stream>>>(srcv, dstv, cursor, csr_src, E, Etot);
  }

  // --- Layer 1 ---
  k_w1t<<<dim3(128), dim3(256), 0, stream>>>(W1, W1t);
  k_gemm1<<<dim3((N + 63)/64), dim3(256), 0, stream>>>(x, W1t, as1, ad1, h1, a_src1, a_dst1, N);
  k_agg1<<<dim3((N + 3)/4), dim3(256), 0, stream>>>((const __half*)h1, a_src1, a_dst1, rowptr, csr_src, b1, h2, N);

  // --- Layer 2 ---
  k_gemm2<<<dim3((N + 15)/16), dim3(256), 0, stream>>>(h2, W2, as2, ad2, hb, a_src2, a_dst2, N);
  k_agg2<<<dim3((N + 3)/4), dim3(256), 0, stream>>>(hb, a_src2, a_dst2, rowptr, csr_src, b2, out, N);
}

// Round 4
// 335.091 us; speedup vs baseline: 1.5118x; 1.1238x over previous
//
#include <hip/hip_runtime.h>
#include <hip/hip_fp16.h>
#include <math.h>

// 2-layer GAT. N=50000, E=800000 (+N self loops), F=128, H=8, C=32, NCLS=16.
// R4: (a) h2 stored fp16 (only consumer is gemm2) -> halves agg1 write;
//     (b) k_gemm2 rewritten as MFMA 16x16x32_f16 (was 512 scalar loads + 256-FMA
//         chain per thread), W2 pre-transposed fp16, a_src2/a_dst2 fused via shfl;
//     (c) k_agg1 unrolled x8 -> x4 -> x1 for more outstanding loads;
//     (d) weight transposes merged into one launch.

typedef _Float16 f16x8 __attribute__((ext_vector_type(8)));
typedef _Float16 f16x4 __attribute__((ext_vector_type(4)));
typedef float    f32x4 __attribute__((ext_vector_type(4)));

__device__ __forceinline__ float lrelu(float v){ return v > 0.f ? v : 0.2f*v; }

// ---------------- weight prep: W1 [128][256]->W1t fp16 [256][128]; W2 [256][16]->W2t fp16 [16][256] ----------------
__global__ void k_wprep(const float* __restrict__ W1, _Float16* __restrict__ W1t,
                        const float* __restrict__ W2, _Float16* __restrict__ W2t){
  int b = blockIdx.x, t = threadIdx.x;
  if (b < 128){
    W1t[t*128 + b] = (_Float16)W1[b*256 + t];
  } else {
    for (int i=t; i<4096; i+=256){ int k=i&255, j=i>>8; W2t[j*256+k] = (_Float16)W2[k*16+j]; }
  }
}

// ---------------- GEMM1 (MFMA): h1 = x @ W1 -> fp16 [N,256], + a_src1/a_dst1 ----------------
__global__ __launch_bounds__(256) void k_gemm1(const float* __restrict__ x,
    const _Float16* __restrict__ W1t, const float* __restrict__ as1,
    const float* __restrict__ ad1, _Float16* __restrict__ h1,
    float* __restrict__ a_src1, float* __restrict__ a_dst1, int N)
{
  __shared__ char smem[33792];              // A-tile (17408 B) then reused for h-repack (33792 B)
  _Float16* As = (_Float16*)smem;           // [64 rows][136 halves] (272 B stride, 16B-aligned)
  int t = threadIdx.x;
  int n0 = blockIdx.x*64;

  #pragma unroll
  for (int it=0; it<8; ++it){
    int c = it*256 + t;
    int row = c >> 5;
    int c4  = c & 31;
    int gr = n0 + row; if (gr > N-1) gr = N-1;
    float4 v = *(const float4*)(x + (size_t)gr*128 + c4*4);
    _Float16* dp = As + row*136 + c4*4;
    dp[0]=(_Float16)v.x; dp[1]=(_Float16)v.y; dp[2]=(_Float16)v.z; dp[3]=(_Float16)v.w;
  }
  __syncthreads();

  int wv = t>>6, lane = t&63;
  int m = lane&15, q = lane>>4;
  int r0w = wv*16;

  f16x8 afr[4];
  #pragma unroll
  for (int ks=0; ks<4; ++ks)
    afr[ks] = *(const f16x8*)((const char*)As + (r0w+m)*272 + ks*64 + q*16);

  f32x4 acc[16];
  #pragma unroll
  for (int ct=0; ct<16; ++ct) acc[ct] = (f32x4){0.f,0.f,0.f,0.f};

  const char* bbase = (const char*)W1t;
  #pragma unroll
  for (int ct=0; ct<16; ++ct){
    const char* bp = bbase + (ct*16 + m)*256 + q*16;
    f16x8 b0 = *(const f16x8*)(bp);
    f16x8 b1 = *(const f16x8*)(bp+64);
    f16x8 b2 = *(const f16x8*)(bp+128);
    f16x8 b3 = *(const f16x8*)(bp+192);
    acc[ct] = __builtin_amdgcn_mfma_f32_16x16x32_f16(afr[0], b0, acc[ct],0,0,0);
    acc[ct] = __builtin_amdgcn_mfma_f32_16x16x32_f16(afr[1], b1, acc[ct],0,0,0);
    acc[ct] = __builtin_amdgcn_mfma_f32_16x16x32_f16(afr[2], b2, acc[ct],0,0,0);
    acc[ct] = __builtin_amdgcn_mfma_f32_16x16x32_f16(afr[3], b3, acc[ct],0,0,0);
  }
  __syncthreads();

  _Float16* Hs = (_Float16*)smem;           // [64][264] halves, 528B stride
  #pragma unroll
  for (int ct=0; ct<16; ++ct){
    #pragma unroll
    for (int r=0; r<4; ++r)
      Hs[(size_t)(r0w + q*4 + r)*264 + ct*16 + m] = (_Float16)acc[ct][r];
  }
  __syncthreads();

  for (int r=0; r<16; ++r){
    int grow = n0 + r0w + r;
    if (grow < N){
      uint2 v = *(const uint2*)((const char*)Hs + (size_t)(r0w+r)*528 + lane*8);
      *(uint2*)((char*)h1 + (size_t)grow*512 + lane*8) = v;
    }
  }

  #pragma unroll
  for (int p=t; p<512; p+=256){
    int row = p>>3, hd = p&7;
    int grow = n0 + row;
    if (grow < N){
      const _Float16* hr = Hs + (size_t)row*264 + hd*32;
      float sa=0.f, sd=0.f;
      #pragma unroll
      for (int c=0; c<32; ++c){
        float hv = (float)hr[c];
        sa += hv * as1[hd*32+c];
        sd += hv * ad1[hd*32+c];
      }
      a_src1[(size_t)grow*8+hd] = sa;
      a_dst1[(size_t)grow*8+hd] = sd;
    }
  }
}

// ---------------- CSR build ----------------
__global__ void k_hist(const int* __restrict__ dstv, int* __restrict__ deg, int E, int Etot) {
  int e = blockIdx.x*blockDim.x + threadIdx.x;
  if (e >= Etot) return;
  int d = (e < E) ? dstv[e] : (e - E);
  atomicAdd(&deg[d], 1);
}

__global__ __launch_bounds__(256) void k_scan1(const int* __restrict__ deg,
    int* __restrict__ rowptr, int* __restrict__ bsum, int N)
{
  __shared__ int lds[256];
  int t = threadIdx.x;
  int base = blockIdx.x*1024 + t*4;
  int v0 = (base+0<N)?deg[base+0]:0;
  int v1 = (base+1<N)?deg[base+1]:0;
  int v2 = (base+2<N)?deg[base+2]:0;
  int v3 = (base+3<N)?deg[base+3]:0;
  int tot = v0+v1+v2+v3;
  lds[t]=tot; __syncthreads();
  for (int off=1; off<256; off<<=1){
    int add = (t>=off)?lds[t-off]:0;
    __syncthreads();
    lds[t] += add;
    __syncthreads();
  }
  int excl = lds[t] - tot;
  if (t==255) bsum[blockIdx.x] = lds[t];
  int run = excl;
  if (base+0<N){ rowptr[base+0]=run; run+=v0; }
  if (base+1<N){ rowptr[base+1]=run; run+=v1; }
  if (base+2<N){ rowptr[base+2]=run; run+=v2; }
  if (base+3<N){ rowptr[base+3]=run; }
}

__global__ __launch_bounds__(256) void k_scan2(int* bsum, int B){
  __shared__ int lds[256];
  int t = threadIdx.x;
  int o = (t<B)?bsum[t]:0;
  lds[t] = o; __syncthreads();
  for (int off=1; off<256; off<<=1){
    int add = (t>=off)?lds[t-off]:0;
    __syncthreads();
    lds[t]+=add;
    __syncthreads();
  }
  if (t<B) bsum[t] = lds[t]-o;
}

__global__ void k_scan3(int* __restrict__ rowptr, int* __restrict__ cursor,
                        const int* __restrict__ bsum, int N, int Etot){
  int i = blockIdx.x*blockDim.x + threadIdx.x;
  if (i < N){
    int r = rowptr[i] + bsum[i>>10];
    rowptr[i] = r;
    cursor[i] = r;
  } else if (i == N) {
    rowptr[N] = Etot;
  }
}

__global__ void k_scatter(const int* __restrict__ srcv, const int* __restrict__ dstv,
                          int* __restrict__ cursor, int* __restrict__ csr_src, int E, int Etot){
  int e = blockIdx.x*blockDim.x + threadIdx.x;
  if (e >= Etot) return;
  int s, d;
  if (e < E){ s = srcv[e]; d = dstv[e]; } else { s = e - E; d = s; }
  int pos = atomicAdd(&cursor[d], 1);
  csr_src[pos] = s;
}

// ---------------- Layer-1 aggregation: wave per dst node, x8/x4/x1 unrolled ----------------
__global__ __launch_bounds__(256) void k_agg1(const __half* __restrict__ h1,
    const float* __restrict__ a_src1, const float* __restrict__ a_dst1,
    const int* __restrict__ rowptr, const int* __restrict__ csr_src,
    const float* __restrict__ bias1, _Float16* __restrict__ h2f, int N)
{
  int wave = (blockIdx.x*blockDim.x + threadIdx.x) >> 6;
  if (wave >= N) return;
  int lane = threadIdx.x & 63;
  int head = lane >> 3;
  float ad = a_dst1[(size_t)wave*8 + head];
  int beg = rowptr[wave], end = rowptr[wave+1];
  float4 acc = make_float4(0.f,0.f,0.f,0.f);
  float wsum = 0.f;
  int i = beg;
  for (; i+8 <= end; i+=8){
    int s[8]; float e[8]; uint2 p[8];
    #pragma unroll
    for (int j=0;j<8;++j) s[j]=csr_src[i+j];
    #pragma unroll
    for (int j=0;j<8;++j){
      e[j]=a_src1[(size_t)s[j]*8+head];
      p[j]=*(const uint2*)((const char*)h1 + (size_t)s[j]*512 + lane*8);
    }
    #pragma unroll
    for (int j=0;j<8;++j){
      float w=__expf(lrelu(e[j]+ad));
      wsum += w;
      const __half2* qq=(const __half2*)&p[j];
      float2 f0=__half22float2(qq[0]), f1=__half22float2(qq[1]);
      acc.x += w*f0.x; acc.y += w*f0.y; acc.z += w*f1.x; acc.w += w*f1.y;
    }
  }
  for (; i+4 <= end; i+=4){
    int s[4]; float e[4]; uint2 p[4];
    #pragma unroll
    for (int j=0;j<4;++j) s[j]=csr_src[i+j];
    #pragma unroll
    for (int j=0;j<4;++j){
      e[j]=a_src1[(size_t)s[j]*8+head];
      p[j]=*(const uint2*)((const char*)h1 + (size_t)s[j]*512 + lane*8);
    }
    #pragma unroll
    for (int j=0;j<4;++j){
      float w=__expf(lrelu(e[j]+ad));
      wsum += w;
      const __half2* qq=(const __half2*)&p[j];
      float2 f0=__half22float2(qq[0]), f1=__half22float2(qq[1]);
      acc.x += w*f0.x; acc.y += w*f0.y; acc.z += w*f1.x; acc.w += w*f1.y;
    }
  }
  for (; i<end; ++i){
    int s = csr_src[i];
    float w = __expf(lrelu(a_src1[(size_t)s*8+head] + ad));
    wsum += w;
    uint2 p = *(const uint2*)((const char*)h1 + (size_t)s*512 + lane*8);
    const __half2* qq=(const __half2*)&p;
    float2 f0=__half22float2(qq[0]), f1=__half22float2(qq[1]);
    acc.x += w*f0.x; acc.y += w*f0.y; acc.z += w*f1.x; acc.w += w*f1.y;
  }
  float dinv = 1.f/(wsum + 1e-16f);
  const float4 bv = *(const float4*)(bias1 + lane*4);
  float4 o;
  o.x = acc.x*dinv + bv.x;
  o.y = acc.y*dinv + bv.y;
  o.z = acc.z*dinv + bv.z;
  o.w = acc.w*dinv + bv.w;
  o.x = o.x > 0.f ? o.x : __expf(o.x)-1.f;
  o.y = o.y > 0.f ? o.y : __expf(o.y)-1.f;
  o.z = o.z > 0.f ? o.z : __expf(o.z)-1.f;
  o.w = o.w > 0.f ? o.w : __expf(o.w)-1.f;
  f16x4 ov = { (_Float16)o.x, (_Float16)o.y, (_Float16)o.z, (_Float16)o.w };
  *(f16x4*)(h2f + (size_t)wave*256 + lane*4) = ov;
}

// ---------------- GEMM2 (MFMA): hb = h2f @ W2 [N,256]@[256,16] fp32 out, + a_src2/a_dst2 ----------------
// Block 256 thr = 4 waves; wave handles 16 nodes; K=256 -> 8 MFMA k-steps.
__global__ __launch_bounds__(256) void k_gemm2(const _Float16* __restrict__ h2f,
    const _Float16* __restrict__ W2t, const float* __restrict__ as2, const float* __restrict__ ad2,
    float* __restrict__ hb, float* __restrict__ a_src2, float* __restrict__ a_dst2, int N)
{
  int t = threadIdx.x, wv = t>>6, lane = t&63;
  int col = lane&15, q = lane>>4;
  int n0 = blockIdx.x*64 + wv*16;
  int am = n0 + col; if (am > N-1) am = N-1;          // A-row node (m = lane&15)

  const _Float16* arow = h2f + (size_t)am*256 + q*8;
  const _Float16* brow = W2t + (size_t)col*256 + q*8;  // B: n = lane&15, k = q*8+j
  f32x4 acc = (f32x4){0.f,0.f,0.f,0.f};
  #pragma unroll
  for (int ks=0; ks<8; ++ks){
    f16x8 a = *(const f16x8*)(arow + ks*32);
    f16x8 b = *(const f16x8*)(brow + ks*32);
    acc = __builtin_amdgcn_mfma_f32_16x16x32_f16(a, b, acc, 0,0,0);
  }

  float vs = as2[col], vd = ad2[col];
  #pragma unroll
  for (int r=0; r<4; ++r){
    int n = n0 + q*4 + r;                              // C/D: row = q*4+r, col = lane&15
    float v = acc[r];
    float pa = v*vs, pd = v*vd;
    #pragma unroll
    for (int msk=8; msk>=1; msk>>=1){ pa += __shfl_xor(pa,msk); pd += __shfl_xor(pd,msk); }
    if (n < N){
      hb[(size_t)n*16 + col] = v;
      if (col==0){ a_src2[n] = pa; a_dst2[n] = pd; }
    }
  }
}

// ---------------- Layer-2 aggregation: wave per dst, 4 edge-groups x 16 ch ----------------
__global__ __launch_bounds__(256) void k_agg2(const float* __restrict__ hb,
    const float* __restrict__ a_src2, const float* __restrict__ a_dst2,
    const int* __restrict__ rowptr, const int* __restrict__ csr_src,
    const float* __restrict__ bias2, float* __restrict__ out, int N)
{
  int wave = (blockIdx.x*blockDim.x + threadIdx.x) >> 6;
  if (wave >= N) return;
  int lane = threadIdx.x & 63;
  int eg   = lane >> 4;
  int ch   = lane & 15;
  float ad = a_dst2[wave];
  int beg = rowptr[wave], end = rowptr[wave+1];
  float acc = 0.f, wsum = 0.f;
  int i = beg + eg;
  for (; i+4 < end; i+=8){
    int s0 = csr_src[i], s1 = csr_src[i+4];
    float e0 = a_src2[s0], e1 = a_src2[s1];
    float h0 = hb[(size_t)s0*16 + ch], h1v = hb[(size_t)s1*16 + ch];
    float w0 = __expf(lrelu(e0 + ad)), w1 = __expf(lrelu(e1 + ad));
    wsum += w0 + w1;
    acc += w0*h0 + w1*h1v;
  }
  for (; i<end; i+=4){
    int s = csr_src[i];
    float w = __expf(lrelu(a_src2[s] + ad));
    wsum += w;
    acc += w * hb[(size_t)s*16 + ch];
  }
  acc  += __shfl_xor(acc, 16);  acc  += __shfl_xor(acc, 32);
  wsum += __shfl_xor(wsum, 16); wsum += __shfl_xor(wsum, 32);
  if (eg == 0)
    out[(size_t)wave*16 + ch] = acc/(wsum + 1e-16f) + bias2[ch];
}

extern "C" void kernel_launch(void* const* d_in, const int* in_sizes, int n_in,
                              void* d_out, int out_size, void* d_ws, size_t ws_size,
                              hipStream_t stream)
{
  const float* x   = (const float*)d_in[0];
  const int*   ei  = (const int*)  d_in[1];
  const float* W1  = (const float*)d_in[2];
  const float* as1 = (const float*)d_in[3];
  const float* ad1 = (const float*)d_in[4];
  const float* b1  = (const float*)d_in[5];
  const float* W2  = (const float*)d_in[6];
  const float* as2 = (const float*)d_in[7];
  const float* ad2 = (const float*)d_in[8];
  const float* b2  = (const float*)d_in[9];
  float* out = (float*)d_out;

  const int N    = in_sizes[0] / 128;       // 50000
  const int E    = in_sizes[1] / 2;         // 800000
  const int Etot = E + N;
  const int* srcv = ei;
  const int* dstv = ei + E;

  char* p = (char*)d_ws;
  auto alloc = [&](size_t bytes)->void* {
    void* r = (void*)p;
    p += (bytes + 255) & ~((size_t)255);
    return r;
  };
  _Float16* h1   = (_Float16*)alloc((size_t)N*256*sizeof(_Float16));
  _Float16* W1t  = (_Float16*)alloc((size_t)256*128*sizeof(_Float16));
  _Float16* h2f  = (_Float16*)alloc((size_t)N*256*sizeof(_Float16));
  _Float16* W2t  = (_Float16*)alloc((size_t)16*256*sizeof(_Float16));
  float* a_src1  = (float*)alloc((size_t)N*8*sizeof(float));
  float* a_dst1  = (float*)alloc((size_t)N*8*sizeof(float));
  float* hb      = (float*)alloc((size_t)N*16*sizeof(float));
  float* a_src2  = (float*)alloc((size_t)N*sizeof(float));
  float* a_dst2  = (float*)alloc((size_t)N*sizeof(float));
  int*   deg     = (int*)alloc((size_t)N*sizeof(int));
  int*   rowptr  = (int*)alloc((size_t)(N+1)*sizeof(int));
  int*   cursor  = (int*)alloc((size_t)N*sizeof(int));
  int*   bsum    = (int*)alloc(256*sizeof(int));
  int*   csr_src = (int*)alloc((size_t)Etot*sizeof(int));

  // --- CSR build ---
  hipMemsetAsync(deg, 0, (size_t)N*sizeof(int), stream);
  {
    dim3 g((Etot + 255)/256), b(256);
    k_hist<<<g, b, 0, stream>>>(dstv, deg, E, Etot);
  }
  int B = (N + 1023)/1024;
  k_scan1<<<dim3(B), dim3(256), 0, stream>>>(deg, rowptr, bsum, N);
  k_scan2<<<dim3(1), dim3(256), 0, stream>>>(bsum, B);
  k_scan3<<<dim3((N + 1 + 255)/256), dim3(256), 0, stream>>>(rowptr, cursor, bsum, N, Etot);
  {
    dim3 g((Etot + 255)/256), b(256);
    k_scatter<<<g, b, 0, stream>>>(srcv, dstv, cursor, csr_src, E, Etot);
  }

  // --- weight prep ---
  k_wprep<<<dim3(129), dim3(256), 0, stream>>>(W1, W1t, W2, W2t);

  // --- Layer 1 ---
  k_gemm1<<<dim3((N + 63)/64), dim3(256), 0, stream>>>(x, W1t, as1, ad1, h1, a_src1, a_dst1, N);
  k_agg1<<<dim3((N + 3)/4), dim3(256), 0, stream>>>((const __half*)h1, a_src1, a_dst1, rowptr, csr_src, b1, h2f, N);

  // --- Layer 2 ---
  k_gemm2<<<dim3((N + 63)/64), dim3(256), 0, stream>>>(h2f, W2t, as2, ad2, hb, a_src2, a_dst2, N);
  k_agg2<<<dim3((N + 3)/4), dim3(256), 0, stream>>>(hb, a_src2, a_dst2, rowptr, csr_src, b2, out, N);
}